// Round 5
// baseline (398.879 us; speedup 1.0000x reference)
//
#include <hip/hip_runtime.h>

// Depthwise 7x7 true-convolution (flipped kernel, SAME zero pad) + mish.
// x: [16,64,256,256] f32, kernel: [7,7] f32 (shared by all planes).
//
// Wave = one full plane row: 64 lanes x 4 cols = 256 = plane width, so every
// load/store instruction is a DENSE contiguous 1 KB across the wave (round-4
// lesson: sparse per-instruction footprints caused 2.4-2.6x HBM partial-line
// amplification). Each wave owns a 32-row band of one plane, streams 38 input
// rows with an 8-slot ring of 4-wide accumulators (static indices only).
// Per input row: 3 aligned float4 loads (cols 4l-4..4l+7, overlap L1-served),
// 7x7x4 FMA into the 7 live output rows, then one completed row: mish + one
// float4 store. No LDS, no barriers, no shuffles.

#define HW 256

__device__ __forceinline__ float mish_f(float y) {
    float t = __expf(y);            // inf-safe: d -> inf -> 2/d -> 0 -> y*1
    float u = 1.0f + t;
    float d = __fmaf_rn(u, u, 1.0f);
    return y * (1.0f - __fdividef(2.0f, d));
}

__global__ __launch_bounds__(256, 4)
void dwconv7_mish_rows(const float* __restrict__ x,
                       const float* __restrict__ kern,
                       float* __restrict__ out) {
    const int tid  = threadIdx.x;
    const int lane = tid & 63;
    const int w    = tid >> 6;                 // wave id in block
    const int task = (blockIdx.x << 2) + w;    // 8192 wave-tasks
    const int plane = task >> 3;               // 0..1023
    const int band  = task & 7;                // 8 bands of 32 rows
    const int r0    = band << 5;

    // Flipped kernel into SGPRs: kf[p*7+q] = kern[6-p][6-q]
    float kf[49];
    #pragma unroll
    for (int i = 0; i < 49; ++i) {
        int p = i / 7, q = i - p * 7;
        kf[i] = __int_as_float(__builtin_amdgcn_readfirstlane(
                    __float_as_int(kern[(6 - p) * 7 + (6 - q)])));
    }

    // Per-lane column bases (clamped; clamped lanes get masked to zero).
    int cA = 4 * lane - 4; if (cA < 0) cA = 0;
    int cC = 4 * lane + 4; if (cC > HW - 4) cC = HW - 4;
    const int pbase = plane << 16;             // plane * 256*256
    const float* __restrict__ pA = x + pbase + cA;
    const float* __restrict__ pB = x + pbase + 4 * lane;
    const float* __restrict__ pC = x + pbase + cC;

    const unsigned mlo = (lane == 0)      ? 0u : 0xffffffffu;
    const unsigned mhi = (lane == 63)     ? 0u : 0xffffffffu;

    float acc[8][4];
    #pragma unroll
    for (int a = 0; a < 8; ++a)
        #pragma unroll
        for (int c = 0; c < 4; ++c) acc[a][c] = 0.f;

    // it = 0..39 ; input row gr = r0+it-3 ; output row od = it-6 completes.
    #pragma unroll 1
    for (int it0 = 0; it0 < 40; it0 += 8) {
        #pragma unroll
        for (int s = 0; s < 8; ++s) {
            const int it = it0 + s;
            const int gr = r0 + it - 3;
            float4 a0, a1, a2;
            if ((unsigned)gr < (unsigned)HW && it < 38) {   // wave-uniform
                const int ro = gr << 8;
                a0 = *(const float4*)(pA + ro);
                a1 = *(const float4*)(pB + ro);
                a2 = *(const float4*)(pC + ro);
            } else {
                a0 = a1 = a2 = make_float4(0.f, 0.f, 0.f, 0.f);
            }
            float v[12] = {a0.x, a0.y, a0.z, a0.w,
                           a1.x, a1.y, a1.z, a1.w,
                           a2.x, a2.y, a2.z, a2.w};
            v[1]  = __uint_as_float(__float_as_uint(v[1])  & mlo);
            v[2]  = __uint_as_float(__float_as_uint(v[2])  & mlo);
            v[3]  = __uint_as_float(__float_as_uint(v[3])  & mlo);
            v[8]  = __uint_as_float(__float_as_uint(v[8])  & mhi);
            v[9]  = __uint_as_float(__float_as_uint(v[9])  & mhi);
            v[10] = __uint_as_float(__float_as_uint(v[10]) & mhi);

            // Input row gr contributes to output rows od = it-p, p=0..6,
            // ring slot (it-p)&7 = (s-p)&7 (static). Out-of-band slots are
            // zero-fed or retired before reuse (see ring analysis).
            #pragma unroll
            for (int p = 0; p < 7; ++p) {
                const int slot = (s - p) & 7;
                #pragma unroll
                for (int q = 0; q < 7; ++q) {
                    const float wq = kf[p * 7 + q];
                    #pragma unroll
                    for (int c = 0; c < 4; ++c)
                        acc[slot][c] = fmaf(v[c + q + 1], wq, acc[slot][c]);
                }
            }

            // Output row od = it-6 complete in slot (s+2)&7.
            const int od = it - 6;
            const int fs = (s + 2) & 7;
            if ((unsigned)od < 32u) {                       // wave-uniform
                float4 o;
                o.x = mish_f(acc[fs][0]);
                o.y = mish_f(acc[fs][1]);
                o.z = mish_f(acc[fs][2]);
                o.w = mish_f(acc[fs][3]);
                *(float4*)(out + pbase + ((r0 + od) << 8) + 4 * lane) = o;
            }
            #pragma unroll
            for (int c = 0; c < 4; ++c) acc[fs][c] = 0.f;   // recycle slot
        }
    }
}

extern "C" void kernel_launch(void* const* d_in, const int* in_sizes, int n_in,
                              void* d_out, int out_size, void* d_ws, size_t ws_size,
                              hipStream_t stream) {
    const float* x = (const float*)d_in[0];
    const float* k = (const float*)d_in[1];
    float* out = (float*)d_out;

    dim3 grid(2048, 1, 1);   // 8192 wave-tasks / 4 waves per block
    dim3 block(256);
    dwconv7_mish_rows<<<grid, block, 0, stream>>>(x, k, out);
}

// Round 6
// 169.088 us; speedup vs baseline: 2.3590x; 2.3590x over previous
//
#include <hip/hip_runtime.h>

// Depthwise 7x7 true-convolution (flipped kernel, SAME zero pad) + mish.
// x: [16,64,256,256] f32, kernel: [7,7] f32 (shared by all planes).
//
// R2-lineage LDS tile structure (proven clean HBM traffic + occupancy),
// upgraded: tile 64w x 64h, thread = 8 cols x 2 rows -> the 8-row input
// window is read once as 4 ds_read_b128 per row (32 reads / 16 outputs).
// Input tile 70 rows x 18 float4 granules, row stride 24 granules (26.9 KB
// -> 5 blocks/CU). XOR swizzle phys = g ^ ((row>>1)&7): per read
// instruction, granule-group residue = a ^ s with a in {k,k+2,k+4,k+6}
// (2 lanes each, from tx) and s covering all 8 residues (from ty pairs,
// rows step 2 so (row>>1) mixes parity) -> uniform 8 words/bank, the
// ds_read_b128 hardware minimum. No spill: waves_per_eu pinned (4,5).

#define HW 256
#define TILE_W 64
#define TILE_H 64
#define LR 70            // input rows: 64 + 6 halo
#define NGD 18           // data granules per row (72 floats: 4-left halo)
#define NGP 24           // padded granule row stride (24%8==0, fits 17^7=22)
#define NSLOT (LR * NGD) // 1260 staging granules

__device__ __forceinline__ float mish_f(float y) {
    float t = __expf(y);            // inf-safe: d -> inf -> 2/d -> 0 -> y*1
    float u = 1.0f + t;
    float d = __fmaf_rn(u, u, 1.0f);
    return y * (1.0f - __fdividef(2.0f, d));
}

__global__ __launch_bounds__(256)
__attribute__((amdgpu_waves_per_eu(4, 5)))
void dwconv7_mish_kernel(const float* __restrict__ x,
                         const float* __restrict__ kern,
                         float* __restrict__ out) {
    __shared__ float4 smem4[LR * NGP];   // 26,880 B -> 5 blocks/CU

    const int tid = threadIdx.x;
    const int tx  = tid & 7;             // 8 strips x 8 cols = 64 wide
    const int ty2 = tid >> 3;            // 32 row-pairs -> 64 rows
    const int col0 = blockIdx.x * TILE_W;
    const int row0 = blockIdx.y * TILE_H;
    const int plane = blockIdx.z;        // b*64 + c

    const float* __restrict__ xp = x + (size_t)plane * (HW * HW);
    float* __restrict__ op = out + (size_t)plane * (HW * HW);

    // Flipped kernel into SGPRs: kf[p*7+q] = kern[6-p][6-q]
    float kf[49];
    #pragma unroll
    for (int i = 0; i < 49; ++i) {
        int p = i / 7, q = i - p * 7;
        kf[i] = __int_as_float(__builtin_amdgcn_readfirstlane(
                    __float_as_int(kern[(6 - p) * 7 + (6 - q)])));
    }

    // Stage input tile: 70 rows x 18 granules. Global float4 loads are
    // 16B-aligned (gc = col0-4+4*c4); each granule fully in-bounds or zero.
    #pragma unroll
    for (int it = 0; it < 5; ++it) {
        int s = tid + it * 256;
        if (s < NSLOT) {
            int r  = s / NGD;
            int c4 = s - r * NGD;
            int gr = row0 - 3 + r;
            int gc = col0 - 4 + c4 * 4;
            float4 v = make_float4(0.f, 0.f, 0.f, 0.f);
            if ((unsigned)gr < (unsigned)HW && (unsigned)gc < (unsigned)HW) {
                v = *(const float4*)(xp + gr * HW + gc);
            }
            smem4[r * NGP + (c4 ^ ((r >> 1) & 7))] = v;
        }
    }
    __syncthreads();

    // Thread: out rows 2*ty2+{0,1}, cols 8*tx..8*tx+7.
    // Input window: LDS rows 2*ty2 .. 2*ty2+7, granules 2tx..2tx+3
    // (window floats v[0..15] = LDS float cols 8tx .. 8tx+15; taps v[1..14]).
    float acc0[8], acc1[8];
    #pragma unroll
    for (int c = 0; c < 8; ++c) { acc0[c] = 0.f; acc1[c] = 0.f; }

    const int g0 = 2 * tx;
    #pragma unroll
    for (int rr = 0; rr < 8; ++rr) {
        const int lr = 2 * ty2 + rr;
        const int sb = (lr >> 1) & 7;
        const float4* base = &smem4[lr * NGP];
        float4 A = base[(g0 + 0) ^ sb];
        float4 B = base[(g0 + 1) ^ sb];
        float4 C = base[(g0 + 2) ^ sb];
        float4 D = base[(g0 + 3) ^ sb];
        float v[16] = {A.x, A.y, A.z, A.w,  B.x, B.y, B.z, B.w,
                       C.x, C.y, C.z, C.w,  D.x, D.y, D.z, D.w};
        // out row j gets kernel row p = rr - j
        if (rr <= 6) {                       // j = 0, p = rr
            #pragma unroll
            for (int q = 0; q < 7; ++q) {
                const float w = kf[rr * 7 + q];
                #pragma unroll
                for (int c = 0; c < 8; ++c)
                    acc0[c] = fmaf(v[c + q + 1], w, acc0[c]);
            }
        }
        if (rr >= 1) {                       // j = 1, p = rr - 1
            #pragma unroll
            for (int q = 0; q < 7; ++q) {
                const float w = kf[(rr - 1) * 7 + q];
                #pragma unroll
                for (int c = 0; c < 8; ++c)
                    acc1[c] = fmaf(v[c + q + 1], w, acc1[c]);
            }
        }
    }

    {
        float4 o0, o1;
        o0.x = mish_f(acc0[0]); o0.y = mish_f(acc0[1]);
        o0.z = mish_f(acc0[2]); o0.w = mish_f(acc0[3]);
        o1.x = mish_f(acc0[4]); o1.y = mish_f(acc0[5]);
        o1.z = mish_f(acc0[6]); o1.w = mish_f(acc0[7]);
        float* dst = op + (row0 + 2 * ty2) * HW + col0 + tx * 8;
        *(float4*)(dst)     = o0;
        *(float4*)(dst + 4) = o1;
    }
    {
        float4 o0, o1;
        o0.x = mish_f(acc1[0]); o0.y = mish_f(acc1[1]);
        o0.z = mish_f(acc1[2]); o0.w = mish_f(acc1[3]);
        o1.x = mish_f(acc1[4]); o1.y = mish_f(acc1[5]);
        o1.z = mish_f(acc1[6]); o1.w = mish_f(acc1[7]);
        float* dst = op + (row0 + 2 * ty2 + 1) * HW + col0 + tx * 8;
        *(float4*)(dst)     = o0;
        *(float4*)(dst + 4) = o1;
    }
}

extern "C" void kernel_launch(void* const* d_in, const int* in_sizes, int n_in,
                              void* d_out, int out_size, void* d_ws, size_t ws_size,
                              hipStream_t stream) {
    const float* x = (const float*)d_in[0];
    const float* k = (const float*)d_in[1];
    float* out = (float*)d_out;

    dim3 grid(HW / TILE_W, HW / TILE_H, 16 * 64);  // 4 x 4 x 1024
    dim3 block(256);
    dwconv7_mish_kernel<<<grid, block, 0, stream>>>(x, k, out);
}